// Round 3
// baseline (245.483 us; speedup 1.0000x reference)
//
#include <hip/hip_runtime.h>
#include <hip/hip_bf16.h>

// Problem: B=16384, J=12, Q=7, O=5, H1=H2=128.  Output: fp32 [B,Q,O].
#define B_TOT 16384
#define NJ 12
#define NQ 7
#define NO 5

// Workspace layout (float indices)
//  W2T : [12][128][128]  combined layer-2 weights, TRANSPOSED [j][h][k], k=i'-1
//  W2B : [12][128]       layer-2 bias row (i'=0)
//  W1C : [12][7][6][128] combined layer-1 weights (natural layout)
//  VC  : [12][7][129][5] combined output weights (natural layout)
//  FLAGS: 2 ints (is_bf16, jid_is_int64)
#define WS_W2T 0
#define WS_W2B (WS_W2T + 12*128*128)
#define WS_W1C (WS_W2B + 12*128)
#define WS_VC  (WS_W1C + 12*7*6*128)
#define WS_TOT (WS_VC  + 12*7*129*5)
#define WS_FLAG_BF16 (WS_TOT)
#define WS_FLAG_J64  (WS_TOT + 1)
#define WS_NEEDED_BYTES ((size_t)(WS_TOT + 2) * 4)

// ---------- load helpers (overloads, no template specialization) ----------
__device__ __forceinline__ float ldf(const float* p) { return *p; }
__device__ __forceinline__ float ldf(const __hip_bfloat16* p) {
    return __bfloat162float(*p);
}

__device__ __forceinline__ float sigmoidf_(float v) {
    return 1.0f / (1.0f + __expf(-v));
}

// ---------- device-side dtype probes (deterministic, wave-uniform) ----------
__device__ __forceinline__ int probe_is_bf16(const unsigned int* w1bits) {
    // bf16 tensors: each 32-bit word = two bf16; low 16 bits are a bf16 xavier
    // weight (exponent ~[100,130] or zero). fp32: low 16 bits = mantissa noise.
    int hits = 0;
    for (int t = 0; t < 64; ++t) {
        unsigned int lo = w1bits[t] & 0xFFFFu;
        unsigned int e = (lo >> 7) & 0xFFu;
        if (lo == 0u || (e >= 100u && e <= 130u)) ++hits;
    }
    return hits >= 32;
}
__device__ __forceinline__ int probe_is_j64(const int* jid) {
    // int64 little-endian: high (odd int32) words all zero for values < 12.
    int o = 0;
    for (int t = 0; t < 64; ++t) o |= jid[2*t + 1];
    return (o == 0) ? 1 : 0;
}

// ---------- weight combine (path A) ----------
template<typename T>
__device__ __forceinline__ void combine_body(
    int idx, const T* W1, const T* W1a, const T* W2, const T* W2a,
    const T* V, const T* Va, float* ws)
{
    if (idx < 12*128*128) {
        int j = idx >> 14, r = idx & 16383, h = r >> 7, k = r & 127, i = k + 1;
        ws[WS_W2T + idx] = ldf(W2 + i*128 + h) + ldf(W2a + (j*129 + i)*128 + h);
    } else if (idx < WS_W1C) {
        int t = idx - WS_W2B;
        int j = t >> 7, h = t & 127;
        ws[WS_W2B + t] = ldf(W2 + h) + ldf(W2a + j*129*128 + h);
    } else if (idx < WS_VC) {
        int t = idx - WS_W1C;
        int j = t / 5376;  int r = t - j*5376;
        ws[WS_W1C + t] = ldf(W1 + r) + ldf(W1a + j*5376 + r);
    } else if (idx < WS_TOT) {
        int t = idx - WS_VC;
        int j = t / 4515;  int r = t - j*4515;
        ws[WS_VC + t] = ldf(V + r) + ldf(Va + j*4515 + r);
    }
}

__global__ __launch_bounds__(256) void combine_kernel(
    const void* W1, const void* W1a, const void* W2, const void* W2a,
    const void* V,  const void* Va,  const int* jid, float* ws)
{
    const int isb = probe_is_bf16((const unsigned int*)W1);
    int idx = blockIdx.x * 256 + threadIdx.x;
    if (idx == 0) {
        ((int*)ws)[WS_FLAG_BF16] = isb;
        ((int*)ws)[WS_FLAG_J64]  = probe_is_j64(jid);
    }
    if (isb) combine_body(idx,
        (const __hip_bfloat16*)W1, (const __hip_bfloat16*)W1a,
        (const __hip_bfloat16*)W2, (const __hip_bfloat16*)W2a,
        (const __hip_bfloat16*)V,  (const __hip_bfloat16*)Va, ws);
    else combine_body(idx,
        (const float*)W1, (const float*)W1a, (const float*)W2,
        (const float*)W2a, (const float*)V, (const float*)Va, ws);
}

// ---------- main kernel, path A: combined fp32 weights from ws ----------
// One wave per b; block = 4 waves; each wave loops over 4 b's. Grid = 1024.
__global__ __launch_bounds__(256) void CalibrationNetwork_81329500717524_kernel(
    const void* xraw, const int* __restrict__ jid,
    const float* __restrict__ ws, float* __restrict__ out)
{
    __shared__ __align__(16) float lds_z1[4][NQ][128];
    const int tid = threadIdx.x;
    const int l = tid & 63, w = tid >> 6;
    const int isb = ((const int*)ws)[WS_FLAG_BF16];
    const int j64 = ((const int*)ws)[WS_FLAG_J64];
    const float* xf = (const float*)xraw;
    const __hip_bfloat16* xb = (const __hip_bfloat16*)xraw;

    #pragma unroll 1
    for (int t = 0; t < 4; ++t) {
        const int b = blockIdx.x * 16 + w * 4 + t;
        const int j = j64 ? jid[2*b] : jid[b];

        float xv = 0.0f;
        if (l < 35) xv = isb ? __bfloat162float(xb[b*35 + l]) : xf[b*35 + l];

        // layer 1
        const float* W1cj = ws + WS_W1C + j*5376;
        #pragma unroll
        for (int q = 0; q < NQ; ++q) {
            const float* Wq = W1cj + q*768;
            float a  = Wq[l];
            float bb = Wq[64 + l];
            #pragma unroll
            for (int i = 1; i <= 5; ++i) {
                float xi = __shfl(xv, q*5 + (i - 1), 64);
                a  = fmaf(xi, Wq[i*128 + l],      a);
                bb = fmaf(xi, Wq[i*128 + 64 + l], bb);
            }
            lds_z1[w][q][l]      = sigmoidf_(a);
            lds_z1[w][q][64 + l] = sigmoidf_(bb);
        }
        __syncthreads();

        // layer 2
        const float* rowA = ws + WS_W2T + j*16384 + l*128;
        const float* rowB = rowA + 64*128;
        const float biasA = ws[WS_W2B + j*128 + l];
        const float biasB = ws[WS_W2B + j*128 + 64 + l];
        float accA[NQ], accB[NQ];
        #pragma unroll
        for (int q = 0; q < NQ; ++q) { accA[q] = biasA; accB[q] = biasB; }

        #pragma unroll 2
        for (int k = 0; k < 128; k += 4) {
            const float4 wA = *(const float4*)(rowA + k);
            const float4 wB = *(const float4*)(rowB + k);
            #pragma unroll
            for (int q = 0; q < NQ; ++q) {
                const float4 z = *(const float4*)(&lds_z1[w][q][k]);
                accA[q] = fmaf(wA.x, z.x, accA[q]);
                accA[q] = fmaf(wA.y, z.y, accA[q]);
                accA[q] = fmaf(wA.z, z.z, accA[q]);
                accA[q] = fmaf(wA.w, z.w, accA[q]);
                accB[q] = fmaf(wB.x, z.x, accB[q]);
                accB[q] = fmaf(wB.y, z.y, accB[q]);
                accB[q] = fmaf(wB.z, z.z, accB[q]);
                accB[q] = fmaf(wB.w, z.w, accB[q]);
            }
        }
        __syncthreads();

        // output layer + softmax
        #pragma unroll 1
        for (int q = 0; q < NQ; ++q) {
            const float zA = sigmoidf_(accA[q]);
            const float zB = sigmoidf_(accB[q]);
            const float* Vcj = ws + WS_VC + j*4515 + q*645;
            const float* vA = Vcj + (1 + l)*5;
            const float* vB = Vcj + (65 + l)*5;
            float p0 = zA*vA[0] + zB*vB[0];
            float p1 = zA*vA[1] + zB*vB[1];
            float p2 = zA*vA[2] + zB*vB[2];
            float p3 = zA*vA[3] + zB*vB[3];
            float p4 = zA*vA[4] + zB*vB[4];
            #pragma unroll
            for (int off = 32; off > 0; off >>= 1) {
                p0 += __shfl_xor(p0, off, 64);
                p1 += __shfl_xor(p1, off, 64);
                p2 += __shfl_xor(p2, off, 64);
                p3 += __shfl_xor(p3, off, 64);
                p4 += __shfl_xor(p4, off, 64);
            }
            p0 += Vcj[0]; p1 += Vcj[1]; p2 += Vcj[2]; p3 += Vcj[3]; p4 += Vcj[4];
            float m = fmaxf(fmaxf(fmaxf(p0, p1), fmaxf(p2, p3)), p4);
            float e0 = __expf(p0 - m), e1 = __expf(p1 - m), e2 = __expf(p2 - m),
                  e3 = __expf(p3 - m), e4 = __expf(p4 - m);
            float inv = 1.0f / (e0 + e1 + e2 + e3 + e4);
            if (l < 5) {
                float v = (l == 0) ? e0 : (l == 1) ? e1 : (l == 2) ? e2
                        : (l == 3) ? e3 : e4;
                out[b*35 + q*5 + l] = v * inv;          // fp32 output
            }
        }
    }
}

// ---------- main kernel, path B: no workspace, combine on the fly ----------
template<typename T>
__device__ void direct_body(
    const T* __restrict__ x, const int* __restrict__ jid, int j64,
    const T* __restrict__ W1, const T* __restrict__ W1a,
    const T* __restrict__ W2, const T* __restrict__ W2a,
    const T* __restrict__ V,  const T* __restrict__ Va,
    float* __restrict__ out, float (*lds_z1)[NQ][128])
{
    const int tid = threadIdx.x;
    const int l = tid & 63, w = tid >> 6;

    #pragma unroll 1
    for (int t = 0; t < 4; ++t) {
        const int b = blockIdx.x * 16 + w * 4 + t;
        const int j = j64 ? jid[2*b] : jid[b];

        float xv = 0.0f;
        if (l < 35) xv = ldf(x + b*35 + l);

        #pragma unroll
        for (int q = 0; q < NQ; ++q) {
            const T* Wq  = W1  + q*768;
            const T* Waq = W1a + j*5376 + q*768;
            float a  = ldf(Wq + l)      + ldf(Waq + l);
            float bb = ldf(Wq + 64 + l) + ldf(Waq + 64 + l);
            #pragma unroll
            for (int i = 1; i <= 5; ++i) {
                float xi = __shfl(xv, q*5 + (i - 1), 64);
                a  = fmaf(xi, ldf(Wq + i*128 + l)      + ldf(Waq + i*128 + l),      a);
                bb = fmaf(xi, ldf(Wq + i*128 + 64 + l) + ldf(Waq + i*128 + 64 + l), bb);
            }
            lds_z1[w][q][l]      = sigmoidf_(a);
            lds_z1[w][q][64 + l] = sigmoidf_(bb);
        }
        __syncthreads();

        float accA[NQ], accB[NQ];
        {
            const float biasA = ldf(W2 + l)      + ldf(W2a + j*129*128 + l);
            const float biasB = ldf(W2 + 64 + l) + ldf(W2a + j*129*128 + 64 + l);
            #pragma unroll
            for (int q = 0; q < NQ; ++q) { accA[q] = biasA; accB[q] = biasB; }
        }
        #pragma unroll 1
        for (int k = 0; k < 128; ++k) {
            const int i = k + 1;
            const float wA = ldf(W2 + i*128 + l)      + ldf(W2a + (j*129 + i)*128 + l);
            const float wB = ldf(W2 + i*128 + 64 + l) + ldf(W2a + (j*129 + i)*128 + 64 + l);
            #pragma unroll
            for (int q = 0; q < NQ; ++q) {
                const float z = lds_z1[w][q][k];
                accA[q] = fmaf(wA, z, accA[q]);
                accB[q] = fmaf(wB, z, accB[q]);
            }
        }
        __syncthreads();

        #pragma unroll 1
        for (int q = 0; q < NQ; ++q) {
            const float zA = sigmoidf_(accA[q]);
            const float zB = sigmoidf_(accB[q]);
            const T* Vq  = V  + q*645;
            const T* Vaq = Va + j*4515 + q*645;
            float p[NO];
            #pragma unroll
            for (int o = 0; o < NO; ++o) {
                float vA = ldf(Vq + (1 + l)*5 + o)  + ldf(Vaq + (1 + l)*5 + o);
                float vB = ldf(Vq + (65 + l)*5 + o) + ldf(Vaq + (65 + l)*5 + o);
                p[o] = zA*vA + zB*vB;
            }
            #pragma unroll
            for (int off = 32; off > 0; off >>= 1) {
                #pragma unroll
                for (int o = 0; o < NO; ++o) p[o] += __shfl_xor(p[o], off, 64);
            }
            #pragma unroll
            for (int o = 0; o < NO; ++o) p[o] += ldf(Vq + o) + ldf(Vaq + o);
            float m = fmaxf(fmaxf(fmaxf(p[0], p[1]), fmaxf(p[2], p[3])), p[4]);
            float e[NO], s = 0.0f;
            #pragma unroll
            for (int o = 0; o < NO; ++o) { e[o] = __expf(p[o] - m); s += e[o]; }
            float inv = 1.0f / s;
            if (l < 5) out[b*35 + q*5 + l] = e[l] * inv;   // fp32 output
        }
    }
}

__global__ __launch_bounds__(256) void calib_direct_kernel(
    const void* x, const int* jid,
    const void* W1, const void* W1a, const void* W2, const void* W2a,
    const void* V,  const void* Va, float* out)
{
    __shared__ __align__(16) float lds_z1[4][NQ][128];
    const int isb = probe_is_bf16((const unsigned int*)W1);
    const int j64 = probe_is_j64(jid);
    if (isb) direct_body(
        (const __hip_bfloat16*)x, jid, j64,
        (const __hip_bfloat16*)W1, (const __hip_bfloat16*)W1a,
        (const __hip_bfloat16*)W2, (const __hip_bfloat16*)W2a,
        (const __hip_bfloat16*)V,  (const __hip_bfloat16*)Va, out, lds_z1);
    else direct_body(
        (const float*)x, jid, j64,
        (const float*)W1, (const float*)W1a, (const float*)W2,
        (const float*)W2a, (const float*)V, (const float*)Va, out, lds_z1);
}

extern "C" void kernel_launch(void* const* d_in, const int* in_sizes, int n_in,
                              void* d_out, int out_size, void* d_ws, size_t ws_size,
                              hipStream_t stream)
{
    const void* x   = d_in[0];
    const int*  jid = (const int*)d_in[1];
    const void* W1  = d_in[2];
    const void* W1a = d_in[3];
    const void* W2  = d_in[4];
    const void* W2a = d_in[5];
    const void* V   = d_in[6];
    const void* Va  = d_in[7];
    float* out = (float*)d_out;

    // Diagnostic pre-fill: byte 0x3E => ~0.186 under both fp32 and bf16 views.
    // Only out_size*2 bytes (safe under either output-dtype interpretation).
    // Overwritten by the main kernel when it runs; distinguishes "kernel didn't
    // launch" (absmax ~0.6) from "kernel_launch never called" (absmax 0.7930).
    hipMemsetAsync(d_out, 0x3E, (size_t)out_size * 2, stream);

    if (ws_size >= WS_NEEDED_BYTES) {
        float* ws = (float*)d_ws;
        combine_kernel<<<(WS_TOT + 255) / 256, 256, 0, stream>>>(
            W1, W1a, W2, W2a, V, Va, jid, ws);
        CalibrationNetwork_81329500717524_kernel<<<B_TOT / 16, 256, 0, stream>>>(
            x, jid, ws, out);
    } else {
        calib_direct_kernel<<<B_TOT / 16, 256, 0, stream>>>(
            x, jid, W1, W1a, W2, W2a, V, Va, out);
    }
}

// Round 4
// 214.290 us; speedup vs baseline: 1.1456x; 1.1456x over previous
//
#include <hip/hip_runtime.h>
#include <hip/hip_bf16.h>

// Problem: B=16384, J=12, Q=7, O=5, H1=H2=128.  Output: fp32 [B,Q,O].
#define B_TOT 16384
#define NQ 7
#define NO 5

// Workspace layout (float indices)
//  W2BF: [12][128][128] ushort bf16, rows i'=1..128, combined W2+W2a  (98304 floats)
//  W2B : [12][128] fp32 combined bias row (i'=0)
//  W1C : [12][7][6][128] fp32 combined layer-1 weights
//  VCP : [12][7][64][12] fp32: lane l's 10 V-weights (rows 1+2l, 2+2l) + 2 pad
//  VCB : [12][7][5] fp32 V bias row (i'=0)
#define WS_W2BF 0
#define WS_W2B  (WS_W2BF + 98304)
#define WS_W1C  (WS_W2B + 1536)
#define WS_VCP  (WS_W1C + 64512)
#define WS_VCB  (WS_VCP + 64512)
#define WS_FLAG_BF16 (WS_VCB + 420)
#define WS_FLAG_J64  (WS_FLAG_BF16 + 1)
#define WS_TOT_FLOATS (WS_FLAG_J64 + 1)
#define WS_NEEDED_BYTES ((size_t)WS_TOT_FLOATS * 4)

// combine index ranges
#define CN0 196608                 // W2BF ushorts
#define CN1 (CN0 + 1536)           // W2B
#define CN2 (CN1 + 64512)          // W1C
#define CN3 (CN2 + 64512)          // VCP
#define CN4 (CN3 + 420)            // VCB
#define C_TOTAL CN4

// ---------- load helpers ----------
__device__ __forceinline__ float ldf(const float* p) { return *p; }
__device__ __forceinline__ float ldf(const __hip_bfloat16* p) {
    return __bfloat162float(*p);
}
__device__ __forceinline__ float sigmoidf_(float v) {
    return 1.0f / (1.0f + __expf(-v));
}

// ---------- device-side dtype probes (deterministic, wave-uniform) ----------
__device__ __forceinline__ int probe_is_bf16(const unsigned int* w1bits) {
    int hits = 0;
    for (int t = 0; t < 64; ++t) {
        unsigned int lo = w1bits[t] & 0xFFFFu;
        unsigned int e = (lo >> 7) & 0xFFu;
        if (lo == 0u || (e >= 100u && e <= 130u)) ++hits;
    }
    return hits >= 32;
}
__device__ __forceinline__ int probe_is_j64(const int* jid) {
    int o = 0;
    for (int t = 0; t < 64; ++t) o |= jid[2*t + 1];
    return (o == 0) ? 1 : 0;
}

// ---------- weight combine ----------
template<typename T>
__device__ __forceinline__ void combine_body(
    int idx, const T* W1, const T* W1a, const T* W2, const T* W2a,
    const T* V, const T* Va, float* ws)
{
    if (idx < CN0) {
        // W2BF[j][i-1][h] bf16 = W2[i][h] + W2a[j][i][h], i = 1..128
        int j = idx >> 14, r = idx & 16383, i = (r >> 7) + 1, h = r & 127;
        float v = ldf(W2 + i*128 + h) + ldf(W2a + (j*129 + i)*128 + h);
        ((__hip_bfloat16*)(ws + WS_W2BF))[idx] = __float2bfloat16(v);
    } else if (idx < CN1) {
        int t = idx - CN0;
        int j = t >> 7, h = t & 127;
        ws[WS_W2B + t] = ldf(W2 + h) + ldf(W2a + j*129*128 + h);
    } else if (idx < CN2) {
        int t = idx - CN1;
        int j = t / 5376;  int r = t - j*5376;
        ws[WS_W1C + t] = ldf(W1 + r) + ldf(W1a + j*5376 + r);
    } else if (idx < CN3) {
        // VCP[j][q][l][c]: c<10 -> Vc[j][q][1+2l .. 2+2l][0..4] flattened
        int t = idx - CN2;
        int j = t / 5376;  int r = t - j*5376;
        int q = r / 768;   int r2 = r - q*768;
        int ln = r2 / 12;  int c = r2 - ln*12;
        float v = 0.0f;
        if (c < 10) {
            int src = q*645 + 5 + 10*ln + c;       // (1+2l)*5 + c
            v = ldf(V + src) + ldf(Va + j*4515 + src);
        }
        ws[WS_VCP + t] = v;
    } else if (idx < CN4) {
        int t = idx - CN3;
        int j = t / 35;  int r = t - j*35;
        int q = r / 5,   o = r - q*5;
        int src = q*645 + o;                        // i'=0 bias row
        ws[WS_VCB + t] = ldf(V + src) + ldf(Va + j*4515 + src);
    }
}

__global__ __launch_bounds__(256) void combine_kernel(
    const void* W1, const void* W1a, const void* W2, const void* W2a,
    const void* V,  const void* Va,  const int* jid, float* ws)
{
    const int isb = probe_is_bf16((const unsigned int*)W1);
    int idx = blockIdx.x * 256 + threadIdx.x;
    if (idx == 0) {
        ((int*)ws)[WS_FLAG_BF16] = isb;
        ((int*)ws)[WS_FLAG_J64]  = probe_is_j64(jid);
    }
    if (idx >= C_TOTAL) return;
    if (isb) combine_body(idx,
        (const __hip_bfloat16*)W1, (const __hip_bfloat16*)W1a,
        (const __hip_bfloat16*)W2, (const __hip_bfloat16*)W2a,
        (const __hip_bfloat16*)V,  (const __hip_bfloat16*)Va, ws);
    else combine_body(idx,
        (const float*)W1, (const float*)W1a, (const float*)W2,
        (const float*)W2a, (const float*)V, (const float*)Va, ws);
}

// ---------- main kernel ----------
// One wave per b; block = 4 waves; each wave loops over 4 b's. Grid = 1024.
// Layer-2 ownership: lane l owns h' = 2l, 2l+1 -> coalesced dword weight loads.
__global__ __launch_bounds__(256) void CalibrationNetwork_81329500717524_kernel(
    const void* xraw, const int* __restrict__ jid,
    const float* __restrict__ ws, float* __restrict__ out)
{
    __shared__ __align__(16) float lds_z1[4][NQ][128];   // 14336 B
    const int tid = threadIdx.x;
    const int l = tid & 63, w = tid >> 6;
    const int isb = ((const int*)ws)[WS_FLAG_BF16];
    const int j64 = ((const int*)ws)[WS_FLAG_J64];
    const float* xf = (const float*)xraw;
    const __hip_bfloat16* xb = (const __hip_bfloat16*)xraw;

    #pragma unroll 1
    for (int t = 0; t < 4; ++t) {
        const int b = blockIdx.x * 16 + w * 4 + t;
        const int j = j64 ? jid[2*b] : jid[b];

        float xv = 0.0f;
        if (l < 35) xv = isb ? __bfloat162float(xb[b*35 + l]) : xf[b*35 + l];

        // ---- layer 1: lane l -> h = l, l+64 (coalesced W1C reads) ----
        const float* W1cj = ws + WS_W1C + j*5376;
        #pragma unroll
        for (int q = 0; q < NQ; ++q) {
            const float* Wq = W1cj + q*768;
            float a  = Wq[l];
            float bb = Wq[64 + l];
            #pragma unroll
            for (int i = 1; i <= 5; ++i) {
                float xi = __shfl(xv, q*5 + (i - 1), 64);
                a  = fmaf(xi, Wq[i*128 + l],      a);
                bb = fmaf(xi, Wq[i*128 + 64 + l], bb);
            }
            lds_z1[w][q][l]      = sigmoidf_(a);
            lds_z1[w][q][64 + l] = sigmoidf_(bb);
        }
        __syncthreads();

        // ---- layer 2: per k, wave reads one 256B segment of bf16 pairs ----
        const unsigned int* W2p =
            (const unsigned int*)(ws + WS_W2BF) + j*8192 + l;   // row k: +k*64
        const float2 bias = *(const float2*)(ws + WS_W2B + j*128 + 2*l);
        float accA[NQ], accB[NQ];
        #pragma unroll
        for (int q = 0; q < NQ; ++q) { accA[q] = bias.x; accB[q] = bias.y; }

        #pragma unroll 2
        for (int k = 0; k < 128; k += 4) {
            float4 z[NQ];
            #pragma unroll
            for (int q = 0; q < NQ; ++q)
                z[q] = *(const float4*)(&lds_z1[w][q][k]);   // wave-uniform: broadcast
            #pragma unroll
            for (int dk = 0; dk < 4; ++dk) {
                unsigned int u = W2p[(k + dk)*64];
                float wlo = __uint_as_float(u << 16);          // h' = 2l
                float whi = __uint_as_float(u & 0xffff0000u);  // h' = 2l+1
                #pragma unroll
                for (int q = 0; q < NQ; ++q) {
                    float zq = (dk == 0) ? z[q].x : (dk == 1) ? z[q].y
                             : (dk == 2) ? z[q].z : z[q].w;
                    accA[q] = fmaf(wlo, zq, accA[q]);
                    accB[q] = fmaf(whi, zq, accB[q]);
                }
            }
        }
        __syncthreads();

        // ---- output layer + softmax ----
        float res = 0.0f;
        #pragma unroll 1
        for (int q = 0; q < NQ; ++q) {
            const float zA = sigmoidf_(accA[q]);   // z2[2l]
            const float zB = sigmoidf_(accB[q]);   // z2[2l+1]
            const float* vp = ws + WS_VCP + ((j*NQ + q)*64 + l)*12;
            const float4 v0 = *(const float4*)(vp);       // vA[0..3]
            const float4 v1 = *(const float4*)(vp + 4);   // vA[4], vB[0..2]
            const float2 v2 = *(const float2*)(vp + 8);   // vB[3..4]
            float p0 = zA*v0.x + zB*v1.y;
            float p1 = zA*v0.y + zB*v1.z;
            float p2 = zA*v0.z + zB*v1.w;
            float p3 = zA*v0.w + zB*v2.x;
            float p4 = zA*v1.x + zB*v2.y;
            #pragma unroll
            for (int off = 32; off > 0; off >>= 1) {
                p0 += __shfl_xor(p0, off, 64);
                p1 += __shfl_xor(p1, off, 64);
                p2 += __shfl_xor(p2, off, 64);
                p3 += __shfl_xor(p3, off, 64);
                p4 += __shfl_xor(p4, off, 64);
            }
            const float* vb = ws + WS_VCB + (j*NQ + q)*5;
            p0 += vb[0]; p1 += vb[1]; p2 += vb[2]; p3 += vb[3]; p4 += vb[4];
            float m = fmaxf(fmaxf(fmaxf(p0, p1), fmaxf(p2, p3)), p4);
            float e0 = __expf(p0 - m), e1 = __expf(p1 - m), e2 = __expf(p2 - m),
                  e3 = __expf(p3 - m), e4 = __expf(p4 - m);
            float inv = 1.0f / (e0 + e1 + e2 + e3 + e4);
            int o = l - q*5;
            if (o >= 0 && o < 5) {
                float v = (o == 0) ? e0 : (o == 1) ? e1 : (o == 2) ? e2
                        : (o == 3) ? e3 : e4;
                res = v * inv;
            }
        }
        if (l < 35) out[b*35 + l] = res;     // one coalesced write per b
    }
}

// ---------- fallback path B: no workspace, combine on the fly ----------
template<typename T>
__device__ void direct_body(
    const T* __restrict__ x, const int* __restrict__ jid, int j64,
    const T* __restrict__ W1, const T* __restrict__ W1a,
    const T* __restrict__ W2, const T* __restrict__ W2a,
    const T* __restrict__ V,  const T* __restrict__ Va,
    float* __restrict__ out, float (*lds_z1)[NQ][128])
{
    const int tid = threadIdx.x;
    const int l = tid & 63, w = tid >> 6;

    #pragma unroll 1
    for (int t = 0; t < 4; ++t) {
        const int b = blockIdx.x * 16 + w * 4 + t;
        const int j = j64 ? jid[2*b] : jid[b];

        float xv = 0.0f;
        if (l < 35) xv = ldf(x + b*35 + l);

        #pragma unroll
        for (int q = 0; q < NQ; ++q) {
            const T* Wq  = W1  + q*768;
            const T* Waq = W1a + j*5376 + q*768;
            float a  = ldf(Wq + l)      + ldf(Waq + l);
            float bb = ldf(Wq + 64 + l) + ldf(Waq + 64 + l);
            #pragma unroll
            for (int i = 1; i <= 5; ++i) {
                float xi = __shfl(xv, q*5 + (i - 1), 64);
                a  = fmaf(xi, ldf(Wq + i*128 + l)      + ldf(Waq + i*128 + l),      a);
                bb = fmaf(xi, ldf(Wq + i*128 + 64 + l) + ldf(Waq + i*128 + 64 + l), bb);
            }
            lds_z1[w][q][l]      = sigmoidf_(a);
            lds_z1[w][q][64 + l] = sigmoidf_(bb);
        }
        __syncthreads();

        float accA[NQ], accB[NQ];
        {
            const float biasA = ldf(W2 + l)      + ldf(W2a + j*129*128 + l);
            const float biasB = ldf(W2 + 64 + l) + ldf(W2a + j*129*128 + 64 + l);
            #pragma unroll
            for (int q = 0; q < NQ; ++q) { accA[q] = biasA; accB[q] = biasB; }
        }
        #pragma unroll 1
        for (int k = 0; k < 128; ++k) {
            const int i = k + 1;
            const float wA = ldf(W2 + i*128 + l)      + ldf(W2a + (j*129 + i)*128 + l);
            const float wB = ldf(W2 + i*128 + 64 + l) + ldf(W2a + (j*129 + i)*128 + 64 + l);
            #pragma unroll
            for (int q = 0; q < NQ; ++q) {
                const float z = lds_z1[w][q][k];
                accA[q] = fmaf(wA, z, accA[q]);
                accB[q] = fmaf(wB, z, accB[q]);
            }
        }
        __syncthreads();

        #pragma unroll 1
        for (int q = 0; q < NQ; ++q) {
            const float zA = sigmoidf_(accA[q]);
            const float zB = sigmoidf_(accB[q]);
            const T* Vq  = V  + q*645;
            const T* Vaq = Va + j*4515 + q*645;
            float p[NO];
            #pragma unroll
            for (int o = 0; o < NO; ++o) {
                float vA = ldf(Vq + (1 + l)*5 + o)  + ldf(Vaq + (1 + l)*5 + o);
                float vB = ldf(Vq + (65 + l)*5 + o) + ldf(Vaq + (65 + l)*5 + o);
                p[o] = zA*vA + zB*vB;
            }
            #pragma unroll
            for (int off = 32; off > 0; off >>= 1) {
                #pragma unroll
                for (int o = 0; o < NO; ++o) p[o] += __shfl_xor(p[o], off, 64);
            }
            #pragma unroll
            for (int o = 0; o < NO; ++o) p[o] += ldf(Vq + o) + ldf(Vaq + o);
            float m = fmaxf(fmaxf(fmaxf(p[0], p[1]), fmaxf(p[2], p[3])), p[4]);
            float e[NO], s = 0.0f;
            #pragma unroll
            for (int o = 0; o < NO; ++o) { e[o] = __expf(p[o] - m); s += e[o]; }
            float inv = 1.0f / s;
            if (l < 5) out[b*35 + q*5 + l] = e[l] * inv;
        }
    }
}

__global__ __launch_bounds__(256) void calib_direct_kernel(
    const void* x, const int* jid,
    const void* W1, const void* W1a, const void* W2, const void* W2a,
    const void* V,  const void* Va, float* out)
{
    __shared__ __align__(16) float lds_z1[4][NQ][128];
    const int isb = probe_is_bf16((const unsigned int*)W1);
    const int j64 = probe_is_j64(jid);
    if (isb) direct_body(
        (const __hip_bfloat16*)x, jid, j64,
        (const __hip_bfloat16*)W1, (const __hip_bfloat16*)W1a,
        (const __hip_bfloat16*)W2, (const __hip_bfloat16*)W2a,
        (const __hip_bfloat16*)V,  (const __hip_bfloat16*)Va, out, lds_z1);
    else direct_body(
        (const float*)x, jid, j64,
        (const float*)W1, (const float*)W1a, (const float*)W2,
        (const float*)W2a, (const float*)V, (const float*)Va, out, lds_z1);
}

extern "C" void kernel_launch(void* const* d_in, const int* in_sizes, int n_in,
                              void* d_out, int out_size, void* d_ws, size_t ws_size,
                              hipStream_t stream)
{
    const void* x   = d_in[0];
    const int*  jid = (const int*)d_in[1];
    const void* W1  = d_in[2];
    const void* W1a = d_in[3];
    const void* W2  = d_in[4];
    const void* W2a = d_in[5];
    const void* V   = d_in[6];
    const void* Va  = d_in[7];
    float* out = (float*)d_out;

    if (ws_size >= WS_NEEDED_BYTES) {
        float* ws = (float*)d_ws;
        combine_kernel<<<(C_TOTAL + 255) / 256, 256, 0, stream>>>(
            W1, W1a, W2, W2a, V, Va, jid, ws);
        CalibrationNetwork_81329500717524_kernel<<<B_TOT / 16, 256, 0, stream>>>(
            x, jid, ws, out);
    } else {
        calib_direct_kernel<<<B_TOT / 16, 256, 0, stream>>>(
            x, jid, W1, W1a, W2, W2a, V, Va, out);
    }
}

// Round 5
// 164.430 us; speedup vs baseline: 1.4929x; 1.3032x over previous
//
#include <hip/hip_runtime.h>
#include <hip/hip_bf16.h>

// Problem: B=16384, J=12, Q=7, O=5, H1=H2=128.  Output: fp32 [B,Q,O].
#define B_TOT 16384
#define NQ 7
#define NO 5

typedef float v2f __attribute__((ext_vector_type(2)));

// Workspace layout (float indices)
//  W2BF: [12][32 kg][64 hp][4 k4] bf16 pairs (h'=2hp,2hp+1), combined W2+W2a rows i'=1..128
//        (98304 floats as backing store; k = kg*4+k4, i' = k+1)
//  W2B : [12][128] fp32 combined bias row (i'=0)
//  W1C : [12][7][6][128] fp32 combined layer-1 weights (natural)
//  VCP : [12][7][64][12] fp32: lane l's 10 V-weights (rows 1+2l, 2+2l) + 2 pad
//  VCB : [12][7][5] fp32 V bias row (i'=0)
#define WS_W2BF 0
#define WS_W2B  (WS_W2BF + 98304)
#define WS_W1C  (WS_W2B + 1536)
#define WS_VCP  (WS_W1C + 64512)
#define WS_VCB  (WS_VCP + 64512)
#define WS_FLAG_BF16 (WS_VCB + 420)
#define WS_FLAG_J64  (WS_FLAG_BF16 + 1)
#define WS_TOT_FLOATS (WS_FLAG_J64 + 1)
#define WS_NEEDED_BYTES ((size_t)WS_TOT_FLOATS * 4)

// combine index ranges
#define CN0 196608                 // W2BF ushorts
#define CN1 (CN0 + 1536)           // W2B
#define CN2 (CN1 + 64512)          // W1C
#define CN3 (CN2 + 64512)          // VCP
#define CN4 (CN3 + 420)            // VCB
#define C_TOTAL CN4

// ---------- helpers ----------
__device__ __forceinline__ float ldf(const float* p) { return *p; }
__device__ __forceinline__ float ldf(const __hip_bfloat16* p) {
    return __bfloat162float(*p);
}
__device__ __forceinline__ float sigmoidf_(float v) {
    return 1.0f / (1.0f + __expf(-v));
}
__device__ __forceinline__ v2f splat2(float s) { v2f r; r.x = s; r.y = s; return r; }
__device__ __forceinline__ v2f unpack_bf2(unsigned int u) {
    v2f r;
    r.x = __uint_as_float(u << 16);          // h' = 2l   (low ushort)
    r.y = __uint_as_float(u & 0xffff0000u);  // h' = 2l+1 (high ushort)
    return r;
}
// DPP wave64 sum -> lane 63 (row_shr 1,2,4,8; row_bcast15; row_bcast31)
#define DPP_ADD_STEP(v, ctrl) \
    v += __int_as_float(__builtin_amdgcn_update_dpp(0, __float_as_int(v), ctrl, 0xf, 0xf, true))
__device__ __forceinline__ float wave_sum63(float v) {
    DPP_ADD_STEP(v, 0x111);
    DPP_ADD_STEP(v, 0x112);
    DPP_ADD_STEP(v, 0x114);
    DPP_ADD_STEP(v, 0x118);
    DPP_ADD_STEP(v, 0x142);
    DPP_ADD_STEP(v, 0x143);
    return v;   // lane 63 holds the full sum
}

// ---------- device-side dtype probes (deterministic, wave-uniform) ----------
__device__ __forceinline__ int probe_is_bf16(const unsigned int* w1bits) {
    int hits = 0;
    for (int t = 0; t < 64; ++t) {
        unsigned int lo = w1bits[t] & 0xFFFFu;
        unsigned int e = (lo >> 7) & 0xFFu;
        if (lo == 0u || (e >= 100u && e <= 130u)) ++hits;
    }
    return hits >= 32;
}
__device__ __forceinline__ int probe_is_j64(const int* jid) {
    int o = 0;
    for (int t = 0; t < 64; ++t) o |= jid[2*t + 1];
    return (o == 0) ? 1 : 0;
}

// ---------- weight combine ----------
template<typename T>
__device__ __forceinline__ void combine_body(
    int idx, const T* W1, const T* W1a, const T* W2, const T* W2a,
    const T* V, const T* Va, float* ws)
{
    if (idx < CN0) {
        // ushort idx -> [j][kg][hp][k4][odd]
        int j = idx >> 14, r = idx & 16383;
        int d = r >> 1, odd = r & 1;
        int kg = d >> 8, rem = d & 255;
        int hp = rem >> 2, k4 = rem & 3;
        int k = kg*4 + k4, i = k + 1, h = hp*2 + odd;
        float v = ldf(W2 + i*128 + h) + ldf(W2a + (j*129 + i)*128 + h);
        ((__hip_bfloat16*)(ws + WS_W2BF))[idx] = __float2bfloat16(v);
    } else if (idx < CN1) {
        int t = idx - CN0;
        int j = t >> 7, h = t & 127;
        ws[WS_W2B + t] = ldf(W2 + h) + ldf(W2a + j*129*128 + h);
    } else if (idx < CN2) {
        int t = idx - CN1;
        int j = t / 5376;  int r = t - j*5376;
        ws[WS_W1C + t] = ldf(W1 + r) + ldf(W1a + j*5376 + r);
    } else if (idx < CN3) {
        // VCP[j][q][l][c]: c<10 -> Vc[j][q][1+2l .. 2+2l][0..4]
        int t = idx - CN2;
        int j = t / 5376;  int r = t - j*5376;
        int q = r / 768;   int r2 = r - q*768;
        int ln = r2 / 12;  int c = r2 - ln*12;
        float v = 0.0f;
        if (c < 10) {
            int src = q*645 + 5 + 10*ln + c;
            v = ldf(V + src) + ldf(Va + j*4515 + src);
        }
        ws[WS_VCP + t] = v;
    } else if (idx < CN4) {
        int t = idx - CN3;
        int j = t / 35;  int r = t - j*35;
        int q = r / 5,   o = r - q*5;
        int src = q*645 + o;
        ws[WS_VCB + t] = ldf(V + src) + ldf(Va + j*4515 + src);
    }
}

__global__ __launch_bounds__(256) void combine_kernel(
    const void* W1, const void* W1a, const void* W2, const void* W2a,
    const void* V,  const void* Va,  const int* jid, float* ws)
{
    const int isb = probe_is_bf16((const unsigned int*)W1);
    int idx = blockIdx.x * 256 + threadIdx.x;
    if (idx == 0) {
        ((int*)ws)[WS_FLAG_BF16] = isb;
        ((int*)ws)[WS_FLAG_J64]  = probe_is_j64(jid);
    }
    if (idx >= C_TOTAL) return;
    if (isb) combine_body(idx,
        (const __hip_bfloat16*)W1, (const __hip_bfloat16*)W1a,
        (const __hip_bfloat16*)W2, (const __hip_bfloat16*)W2a,
        (const __hip_bfloat16*)V,  (const __hip_bfloat16*)Va, ws);
    else combine_body(idx,
        (const float*)W1, (const float*)W1a, (const float*)W2,
        (const float*)W2a, (const float*)V, (const float*)Va, ws);
}

// ---------- main kernel ----------
// One wave per b; block = 4 waves = 4 b's. Grid = 4096 -> 16 blocks/CU queued,
// 8 resident (32-wave cap; LDS 14.3KB*8=115KB fits; VGPR target <=64).
__global__ __launch_bounds__(256, 8) void CalibrationNetwork_81329500717524_kernel(
    const void* xraw, const int* __restrict__ jid,
    const float* __restrict__ ws, float* __restrict__ out)
{
    __shared__ __align__(16) float lds_z1[4][NQ][128];   // 14336 B
    const int tid = threadIdx.x;
    const int l = tid & 63, w = tid >> 6;
    const int isb = ((const int*)ws)[WS_FLAG_BF16];
    const int j64 = ((const int*)ws)[WS_FLAG_J64];

    const int b  = blockIdx.x * 4 + w;
    const int bu = __builtin_amdgcn_readfirstlane(b);
    const int ju = __builtin_amdgcn_readfirstlane(j64 ? jid[2*bu] : jid[bu]);

    // ---- x[b]: wave-uniform -> scalar loads into SGPRs ----
    float xs[35];
    if (isb) {
        const __hip_bfloat16* xp = (const __hip_bfloat16*)xraw + bu*35;
        #pragma unroll
        for (int i = 0; i < 35; ++i) xs[i] = ldf(xp + i);
    } else {
        const float* xp = (const float*)xraw + bu*35;
        #pragma unroll
        for (int i = 0; i < 35; ++i) xs[i] = xp[i];
    }

    // ---- layer 1: lane l owns h = 2l, 2l+1 (paired, pk_fma) ----
    const float* W1cj = ws + WS_W1C + ju*5376;
    #pragma unroll
    for (int q = 0; q < NQ; ++q) {
        const float* Wq = W1cj + q*768;
        v2f a = *(const v2f*)(Wq + 2*l);                  // bias row i'=0
        #pragma unroll
        for (int i = 1; i <= 5; ++i) {
            v2f wv = *(const v2f*)(Wq + i*128 + 2*l);
            a = __builtin_elementwise_fma(wv, splat2(xs[q*5 + i - 1]), a);
        }
        v2f zv; zv.x = sigmoidf_(a.x); zv.y = sigmoidf_(a.y);
        *(v2f*)(&lds_z1[w][q][2*l]) = zv;
    }
    __syncthreads();

    // ---- layer 2: lane l owns h' = 2l, 2l+1; one dwordx4 = 4 k's ----
    const uint4* W2p = (const uint4*)(ws + WS_W2BF) + ju*2048 + l;
    v2f acc[NQ];
    {
        const v2f bias = *(const v2f*)(ws + WS_W2B + ju*128 + 2*l);
        #pragma unroll
        for (int q = 0; q < NQ; ++q) acc[q] = bias;
    }
    #pragma unroll 2
    for (int kg = 0; kg < 32; ++kg) {
        const uint4 u = W2p[kg*64];
        const v2f w0 = unpack_bf2(u.x), w1 = unpack_bf2(u.y),
                  w2 = unpack_bf2(u.z), w3 = unpack_bf2(u.w);
        #pragma unroll
        for (int q = 0; q < NQ; ++q) {
            const float4 z = *(const float4*)(&lds_z1[w][q][kg*4]);  // broadcast
            acc[q] = __builtin_elementwise_fma(w0, splat2(z.x), acc[q]);
            acc[q] = __builtin_elementwise_fma(w1, splat2(z.y), acc[q]);
            acc[q] = __builtin_elementwise_fma(w2, splat2(z.z), acc[q]);
            acc[q] = __builtin_elementwise_fma(w3, splat2(z.w), acc[q]);
        }
    }

    // ---- output layer + softmax (DPP reduction, no LDS) ----
    float res = 0.0f;
    #pragma unroll 1
    for (int q = 0; q < NQ; ++q) {
        const float zA = sigmoidf_(acc[q].x);   // z2[2l]
        const float zB = sigmoidf_(acc[q].y);   // z2[2l+1]
        const float* vp = ws + WS_VCP + ((ju*NQ + q)*64 + l)*12;
        const float4 v0 = *(const float4*)(vp);       // vA[0..3]
        const float4 v1 = *(const float4*)(vp + 4);   // vA[4], vB[0..2]
        const float2 v2 = *(const float2*)(vp + 8);   // vB[3..4]
        float p0 = zA*v0.x + zB*v1.y;
        float p1 = zA*v0.y + zB*v1.z;
        float p2 = zA*v0.z + zB*v1.w;
        float p3 = zA*v0.w + zB*v2.x;
        float p4 = zA*v1.x + zB*v2.y;
        p0 = __shfl(wave_sum63(p0), 63, 64);
        p1 = __shfl(wave_sum63(p1), 63, 64);
        p2 = __shfl(wave_sum63(p2), 63, 64);
        p3 = __shfl(wave_sum63(p3), 63, 64);
        p4 = __shfl(wave_sum63(p4), 63, 64);
        const float* vb = ws + WS_VCB + (ju*NQ + q)*5;
        p0 += vb[0]; p1 += vb[1]; p2 += vb[2]; p3 += vb[3]; p4 += vb[4];
        float m = fmaxf(fmaxf(fmaxf(p0, p1), fmaxf(p2, p3)), p4);
        float e0 = __expf(p0 - m), e1 = __expf(p1 - m), e2 = __expf(p2 - m),
              e3 = __expf(p3 - m), e4 = __expf(p4 - m);
        float inv = 1.0f / (e0 + e1 + e2 + e3 + e4);
        int o = l - q*5;
        if (o >= 0 && o < 5) {
            float v = (o == 0) ? e0 : (o == 1) ? e1 : (o == 2) ? e2
                    : (o == 3) ? e3 : e4;
            res = v * inv;
        }
    }
    if (l < 35) out[b*35 + l] = res;     // one coalesced 140B store per b
}

// ---------- fallback path B: no workspace, combine on the fly ----------
template<typename T>
__device__ void direct_body(
    const T* __restrict__ x, const int* __restrict__ jid, int j64,
    const T* __restrict__ W1, const T* __restrict__ W1a,
    const T* __restrict__ W2, const T* __restrict__ W2a,
    const T* __restrict__ V,  const T* __restrict__ Va,
    float* __restrict__ out, float (*lds_z1)[NQ][128])
{
    const int tid = threadIdx.x;
    const int l = tid & 63, w = tid >> 6;

    #pragma unroll 1
    for (int t = 0; t < 4; ++t) {
        const int b = blockIdx.x * 16 + w * 4 + t;
        const int j = j64 ? jid[2*b] : jid[b];

        float xv = 0.0f;
        if (l < 35) xv = ldf(x + b*35 + l);

        #pragma unroll
        for (int q = 0; q < NQ; ++q) {
            const T* Wq  = W1  + q*768;
            const T* Waq = W1a + j*5376 + q*768;
            float a  = ldf(Wq + l)      + ldf(Waq + l);
            float bb = ldf(Wq + 64 + l) + ldf(Waq + 64 + l);
            #pragma unroll
            for (int i = 1; i <= 5; ++i) {
                float xi = __shfl(xv, q*5 + (i - 1), 64);
                a  = fmaf(xi, ldf(Wq + i*128 + l)      + ldf(Waq + i*128 + l),      a);
                bb = fmaf(xi, ldf(Wq + i*128 + 64 + l) + ldf(Waq + i*128 + 64 + l), bb);
            }
            lds_z1[w][q][l]      = sigmoidf_(a);
            lds_z1[w][q][64 + l] = sigmoidf_(bb);
        }
        __syncthreads();

        float accA[NQ], accB[NQ];
        {
            const float biasA = ldf(W2 + l)      + ldf(W2a + j*129*128 + l);
            const float biasB = ldf(W2 + 64 + l) + ldf(W2a + j*129*128 + 64 + l);
            #pragma unroll
            for (int q = 0; q < NQ; ++q) { accA[q] = biasA; accB[q] = biasB; }
        }
        #pragma unroll 1
        for (int k = 0; k < 128; ++k) {
            const int i = k + 1;
            const float wA = ldf(W2 + i*128 + l)      + ldf(W2a + (j*129 + i)*128 + l);
            const float wB = ldf(W2 + i*128 + 64 + l) + ldf(W2a + (j*129 + i)*128 + 64 + l);
            #pragma unroll
            for (int q = 0; q < NQ; ++q) {
                const float z = lds_z1[w][q][k];
                accA[q] = fmaf(wA, z, accA[q]);
                accB[q] = fmaf(wB, z, accB[q]);
            }
        }
        __syncthreads();

        #pragma unroll 1
        for (int q = 0; q < NQ; ++q) {
            const float zA = sigmoidf_(accA[q]);
            const float zB = sigmoidf_(accB[q]);
            const T* Vq  = V  + q*645;
            const T* Vaq = Va + j*4515 + q*645;
            float p[NO];
            #pragma unroll
            for (int o = 0; o < NO; ++o) {
                float vA = ldf(Vq + (1 + l)*5 + o)  + ldf(Vaq + (1 + l)*5 + o);
                float vB = ldf(Vq + (65 + l)*5 + o) + ldf(Vaq + (65 + l)*5 + o);
                p[o] = zA*vA + zB*vB;
            }
            #pragma unroll
            for (int off = 32; off > 0; off >>= 1) {
                #pragma unroll
                for (int o = 0; o < NO; ++o) p[o] += __shfl_xor(p[o], off, 64);
            }
            #pragma unroll
            for (int o = 0; o < NO; ++o) p[o] += ldf(Vq + o) + ldf(Vaq + o);
            float m = fmaxf(fmaxf(fmaxf(p[0], p[1]), fmaxf(p[2], p[3])), p[4]);
            float e[NO], s = 0.0f;
            #pragma unroll
            for (int o = 0; o < NO; ++o) { e[o] = __expf(p[o] - m); s += e[o]; }
            float inv = 1.0f / s;
            if (l < 5) out[b*35 + q*5 + l] = e[l] * inv;
        }
    }
}

__global__ __launch_bounds__(256) void calib_direct_kernel(
    const void* x, const int* jid,
    const void* W1, const void* W1a, const void* W2, const void* W2a,
    const void* V,  const void* Va, float* out)
{
    __shared__ __align__(16) float lds_z1[4][NQ][128];
    const int isb = probe_is_bf16((const unsigned int*)W1);
    const int j64 = probe_is_j64(jid);
    if (isb) direct_body(
        (const __hip_bfloat16*)x, jid, j64,
        (const __hip_bfloat16*)W1, (const __hip_bfloat16*)W1a,
        (const __hip_bfloat16*)W2, (const __hip_bfloat16*)W2a,
        (const __hip_bfloat16*)V,  (const __hip_bfloat16*)Va, out, lds_z1);
    else direct_body(
        (const float*)x, jid, j64,
        (const float*)W1, (const float*)W1a, (const float*)W2,
        (const float*)W2a, (const float*)V, (const float*)Va, out, lds_z1);
}

extern "C" void kernel_launch(void* const* d_in, const int* in_sizes, int n_in,
                              void* d_out, int out_size, void* d_ws, size_t ws_size,
                              hipStream_t stream)
{
    const void* x   = d_in[0];
    const int*  jid = (const int*)d_in[1];
    const void* W1  = d_in[2];
    const void* W1a = d_in[3];
    const void* W2  = d_in[4];
    const void* W2a = d_in[5];
    const void* V   = d_in[6];
    const void* Va  = d_in[7];
    float* out = (float*)d_out;

    if (ws_size >= WS_NEEDED_BYTES) {
        float* ws = (float*)d_ws;
        combine_kernel<<<(C_TOTAL + 255) / 256, 256, 0, stream>>>(
            W1, W1a, W2, W2a, V, Va, jid, ws);
        CalibrationNetwork_81329500717524_kernel<<<B_TOT / 4, 256, 0, stream>>>(
            x, jid, ws, out);
    } else {
        calib_direct_kernel<<<B_TOT / 16, 256, 0, stream>>>(
            x, jid, W1, W1a, W2, W2a, V, Va, out);
    }
}